// Round 5
// baseline (490.266 us; speedup 1.0000x reference)
//
#include <hip/hip_runtime.h>
#include <hip/hip_bf16.h>
#include <cstdint>
#include <cstddef>

typedef float f32x4 __attribute__((ext_vector_type(4)));
typedef short s16x8 __attribute__((ext_vector_type(8)));

__device__ inline unsigned short f32_to_bf16(float f) {
  union { float f; unsigned int u; } v; v.f = f;
  unsigned int u = v.u;
  u += 0x7fffu + ((u >> 16) & 1u);   // RNE
  return (unsigned short)(u >> 16);
}
__device__ inline float u2f(unsigned int u) {
  union { unsigned int u; float f; } v; v.u = u; return v.f;
}
__device__ inline float bf16lo(unsigned int w) { return u2f(w << 16); }
__device__ inline float bf16hi(unsigned int w) { return u2f(w & 0xffff0000u); }

// 16-lane rotate-reduce via DPP row_ror (all 16 lanes end with the sum)
template <int CTRL>
__device__ inline float dpp_add(float x) {
  int v = __builtin_bit_cast(int, x);
  int r = __builtin_amdgcn_update_dpp(0, v, CTRL, 0xf, 0xf, true);
  return x + __builtin_bit_cast(float, r);
}
__device__ inline float dpp16_sum(float x) {
  x = dpp_add<0x121>(x);  // row_ror:1
  x = dpp_add<0x122>(x);  // row_ror:2
  x = dpp_add<0x124>(x);  // row_ror:4
  x = dpp_add<0x128>(x);  // row_ror:8
  return x;
}

// ---------------------------------------------------------------------------
// kO: out init with bias (kD atomically accumulates on top)
// ---------------------------------------------------------------------------
__global__ __launch_bounds__(256) void kO(const float* __restrict__ bo,
                                          float* __restrict__ out) {
  int idx = blockIdx.x * 256 + threadIdx.x;   // 65536 float4
  int r = idx >> 4, c4 = idx & 15;
  float b = bo[r];
  float4 v; v.x = b; v.y = b; v.z = b; v.w = b;
  *(float4*)(out + (size_t)r * 64 + c4 * 4) = v;
}

// ---------------------------------------------------------------------------
// kX: x fp32 [4096 h][64 c]  ->  xhT bf16 [64 c][4096 h]   (B^T operand for kA)
// ---------------------------------------------------------------------------
__global__ __launch_bounds__(256) void kX(const float* __restrict__ x,
                                          unsigned short* __restrict__ xhT) {
  __shared__ float Ts[64][65];
  int t = threadIdx.x;
  int h0 = blockIdx.x * 64;
#pragma unroll
  for (int i = 0; i < 4; i++) {
    int fi = t + i * 256;            // 1024 float4
    int h = fi >> 4, c4 = fi & 15;
    float4 v = *(const float4*)(x + (size_t)(h0 + h) * 64 + c4 * 4);
    Ts[h][c4 * 4 + 0] = v.x; Ts[h][c4 * 4 + 1] = v.y;
    Ts[h][c4 * 4 + 2] = v.z; Ts[h][c4 * 4 + 3] = v.w;
  }
  __syncthreads();
  int c = t >> 2, q4 = t & 3;
#pragma unroll
  for (int half = 0; half < 2; half++) {
    int h8 = q4 * 8 + half * 32;
    unsigned short u[8];
#pragma unroll
    for (int j = 0; j < 8; j++) u[j] = f32_to_bf16(Ts[h8 + j][c]);
    uint4 p;
    p.x = (unsigned)u[0] | ((unsigned)u[1] << 16);
    p.y = (unsigned)u[2] | ((unsigned)u[3] << 16);
    p.z = (unsigned)u[4] | ((unsigned)u[5] << 16);
    p.w = (unsigned)u[6] | ((unsigned)u[7] << 16);
    *(uint4*)(xhT + (size_t)c * 4096 + h0 + h8) = p;
  }
}

// ---------------------------------------------------------------------------
// kB: alpha/beta = sigmoid(Wa/Wb @ x + b). 64 blocks (one per output row),
// 4-way K-split across threads, 4 independent accumulators.
// ---------------------------------------------------------------------------
__global__ __launch_bounds__(256) void kB(const float* __restrict__ Wa,
                                          const float* __restrict__ ba,
                                          const float* __restrict__ Wb,
                                          const float* __restrict__ bbb,
                                          const float* __restrict__ x,
                                          float* __restrict__ ab,
                                          float* __restrict__ bb2) {
  __shared__ float red[256];
  int t = threadIdx.x;
  int row = blockIdx.x;            // 0..63
  int c = t & 63, kp = t >> 6;     // 4 k-parts of 1024
  const float* Wr = (row < 32) ? (Wa + (size_t)row * 4096)
                               : (Wb + (size_t)(row - 32) * 4096);
  int kb = kp * 1024;
  float a0 = 0.f, a1 = 0.f, a2 = 0.f, a3 = 0.f;
#pragma unroll 4
  for (int k = 0; k < 1024; k += 4) {
    a0 += Wr[kb + k + 0] * x[(size_t)(kb + k + 0) * 64 + c];
    a1 += Wr[kb + k + 1] * x[(size_t)(kb + k + 1) * 64 + c];
    a2 += Wr[kb + k + 2] * x[(size_t)(kb + k + 2) * 64 + c];
    a3 += Wr[kb + k + 3] * x[(size_t)(kb + k + 3) * 64 + c];
  }
  red[t] = (a0 + a1) + (a2 + a3);
  __syncthreads();
  if (t < 64) {
    float s = red[t] + red[t + 64] + red[t + 128] + red[t + 192];
    float z = s + (row < 32 ? ba[row] : bbb[row - 32]);
    float sg = 1.f / (1.f + __expf(-z));
    if (row < 32) ab[(size_t)row * 64 + t] = sg;
    else          bb2[(size_t)(row - 32) * 64 + t] = sg;
  }
}

// ---------------------------------------------------------------------------
// kA: fused QKV GEMM (bf16 MFMA, W streamed fp32->bf16) + causal conv + SiLU
// grid 384 (3 mats x 128 row-tiles of 32), block 128 (2 waves), BK=128
// ---------------------------------------------------------------------------
struct SmemA {
  union {
    struct { unsigned short Wt[32][136]; unsigned short Xt[64][136]; } s;
    float Qs[32][65];
  };
};

__global__ __launch_bounds__(128) void kA(
    const float* __restrict__ Wq, const float* __restrict__ Wk, const float* __restrict__ Wv,
    const float* __restrict__ bq, const float* __restrict__ bk, const float* __restrict__ bv,
    const float* __restrict__ cwq, const float* __restrict__ cwk, const float* __restrict__ cwv,
    const float* __restrict__ cbq, const float* __restrict__ cbk, const float* __restrict__ cbv,
    const unsigned short* __restrict__ xhT, float* __restrict__ qkvb) {
  __shared__ SmemA sm;
  int t = threadIdx.x;
  int gr0 = blockIdx.x * 32;          // global stacked row (0..12287)
  int mat = gr0 >> 12;
  int wr0 = gr0 & 4095;
  const float* W = (mat == 0) ? Wq : ((mat == 1) ? Wk : Wv);
  int l = t & 63, w = t >> 6;
  int lo = l & 15, hi = l >> 4;

  f32x4 acc[4];
#pragma unroll
  for (int cf = 0; cf < 4; cf++) acc[cf] = f32x4{0.f, 0.f, 0.f, 0.f};

  for (int k0 = 0; k0 < 4096; k0 += 128) {
    float4 wv[8];
#pragma unroll
    for (int i = 0; i < 8; i++) {
      int fi = t + i * 128;
      int row = fi >> 5, k4 = fi & 31;
      wv[i] = *(const float4*)(W + (size_t)(wr0 + row) * 4096 + k0 + k4 * 4);
    }
    uint4 xv[8];
#pragma unroll
    for (int i = 0; i < 8; i++) {
      int fi = t + i * 128;
      int c = fi >> 4, k8 = fi & 15;
      xv[i] = *(const uint4*)(xhT + (size_t)c * 4096 + k0 + k8 * 8);
    }
#pragma unroll
    for (int i = 0; i < 8; i++) {
      int fi = t + i * 128;
      int row = fi >> 5, k4 = fi & 31;
      unsigned short u0 = f32_to_bf16(wv[i].x), u1 = f32_to_bf16(wv[i].y);
      unsigned short u2 = f32_to_bf16(wv[i].z), u3 = f32_to_bf16(wv[i].w);
      uint2 p;
      p.x = (unsigned)u0 | ((unsigned)u1 << 16);
      p.y = (unsigned)u2 | ((unsigned)u3 << 16);
      *(uint2*)&sm.s.Wt[row][k4 * 4] = p;
    }
#pragma unroll
    for (int i = 0; i < 8; i++) {
      int fi = t + i * 128;
      int c = fi >> 4, k8 = fi & 15;
      *(uint4*)&sm.s.Xt[c][k8 * 8] = xv[i];
    }
    __syncthreads();
#pragma unroll
    for (int ks = 0; ks < 128; ks += 32) {
      s16x8 a = *(const s16x8*)&sm.s.Wt[(w << 4) + lo][ks + hi * 8];
#pragma unroll
      for (int cf = 0; cf < 4; cf++) {
        s16x8 bfr = *(const s16x8*)&sm.s.Xt[cf * 16 + lo][ks + hi * 8];
        asm volatile("v_mfma_f32_16x16x32_bf16 %0, %1, %2, %0"
                     : "+v"(acc[cf]) : "v"(a), "v"(bfr));
      }
    }
    __syncthreads();
  }
  asm volatile("s_nop 7\n\ts_nop 7\n\ts_nop 7" ::);
  // C/D layout: row = (lane>>4)*4 + reg, col = lane&15
#pragma unroll
  for (int cf = 0; cf < 4; cf++)
#pragma unroll
    for (int p = 0; p < 4; p++)
      sm.Qs[(w << 4) + hi * 4 + p][cf * 16 + lo] = acc[cf][p];
  __syncthreads();

  // conv (causal, K=4) + bias-before-conv + conv-bias + SiLU
  const float* bmat = (mat == 0) ? bq : ((mat == 1) ? bk : bv);
  const float* cw = (mat == 0) ? cwq : ((mat == 1) ? cwk : cwv);
  const float* cb = (mat == 0) ? cbq : ((mat == 1) ? cbk : cbv);
  int row = t >> 2, c0 = (t & 3) * 16;
  float bias = bmat[wr0 + row];
  float w0 = cw[(wr0 + row) * 4 + 0], w1 = cw[(wr0 + row) * 4 + 1];
  float w2 = cw[(wr0 + row) * 4 + 2], w3 = cw[(wr0 + row) * 4 + 3];
  float cbias = cb[wr0 + row];
  float o16[16];
#pragma unroll
  for (int jj = 0; jj < 16; jj++) {
    int c = c0 + jj;
    float s = 0.f, v; int cc;
    cc = c - 3; v = (cc >= 0) ? (sm.Qs[row][cc] + bias) : 0.f; s += v * w0;
    cc = c - 2; v = (cc >= 0) ? (sm.Qs[row][cc] + bias) : 0.f; s += v * w1;
    cc = c - 1; v = (cc >= 0) ? (sm.Qs[row][cc] + bias) : 0.f; s += v * w2;
    v = sm.Qs[row][c] + bias; s += v * w3;
    float z = s + cbias;
    o16[jj] = z / (1.f + __expf(-z));
  }
#pragma unroll
  for (int j4 = 0; j4 < 4; j4++) {
    float4 o;
    o.x = o16[j4 * 4]; o.y = o16[j4 * 4 + 1]; o.z = o16[j4 * 4 + 2]; o.w = o16[j4 * 4 + 3];
    *(float4*)(qkvb + (size_t)(gr0 + row) * 64 + c0 + j4 * 4) = o;
  }
}

// ---------------------------------------------------------------------------
// kC: delta-rule scan. grid 256 = 32 heads x 8 e-groups (16 cols each).
// thread: el = t>>4 (e), dg = t&15 (d-group of 8). State S[8] in registers.
// d-reduction = DPP rotate-reduce within contiguous 16-lane rows; the 64-step
// loop has ZERO barriers.
// ---------------------------------------------------------------------------
__global__ __launch_bounds__(256) void kC(const float* __restrict__ qkvb,
                                          const float* __restrict__ ab,
                                          const float* __restrict__ bb2,
                                          const float* __restrict__ state0,
                                          unsigned short* __restrict__ obT) {
  __shared__ unsigned short Qs[64][136];  // [c][d] bf16, l2-normalized
  __shared__ unsigned short Ks[64][136];
  __shared__ float Vs[64][17];            // [c][e_local]
  __shared__ float Os[64][17];
  __shared__ float As[64], Bs[64];
  __shared__ float red[256], red2[256];
  __shared__ float rqs[64], rks[64];

  int t = threadIdx.x;
  int h = blockIdx.x >> 3, eg = blockIdx.x & 7;
  int e0 = eg * 16;

  // stage q,k transposed to [c][d] bf16
#pragma unroll
  for (int i = 0; i < 8; i++) {
    int fi = t + i * 256;
    int d = fi >> 4, c4 = fi & 15;
    float4 qv = *(const float4*)(qkvb + (size_t)(h * 128 + d) * 64 + c4 * 4);
    float4 kv = *(const float4*)(qkvb + (size_t)(4096 + h * 128 + d) * 64 + c4 * 4);
    const float* qp = (const float*)&qv;
    const float* kp = (const float*)&kv;
#pragma unroll
    for (int j = 0; j < 4; j++) {
      Qs[c4 * 4 + j][d] = f32_to_bf16(qp[j]);
      Ks[c4 * 4 + j][d] = f32_to_bf16(kp[j]);
    }
  }
  {
    int elr = t >> 4, c4 = t & 15;
    float4 vv = *(const float4*)(qkvb + (size_t)(8192 + h * 128 + e0 + elr) * 64 + c4 * 4);
    const float* vp = (const float*)&vv;
#pragma unroll
    for (int j = 0; j < 4; j++) Vs[c4 * 4 + j][elr] = vp[j];
  }
  if (t < 64) { As[t] = ab[h * 64 + t]; Bs[t] = bb2[h * 64 + t]; }
  __syncthreads();

  // l2 norms per (c): sum over d of q^2, k^2
  {
    int c = t >> 2, part = t & 3;
    float sq = 0.f, sk = 0.f;
#pragma unroll
    for (int j = 0; j < 32; j++) {
      float qv = u2f(((unsigned)Qs[c][part + 4 * j]) << 16);
      float kv = u2f(((unsigned)Ks[c][part + 4 * j]) << 16);
      sq += qv * qv; sk += kv * kv;
    }
    red[t] = sq; red2[t] = sk;
  }
  __syncthreads();
  if (t < 64) {
    float sq = red[t * 4] + red[t * 4 + 1] + red[t * 4 + 2] + red[t * 4 + 3];
    float sk = red2[t * 4] + red2[t * 4 + 1] + red2[t * 4 + 2] + red2[t * 4 + 3];
    rqs[t] = rsqrtf(sq + 1e-6f);
    rks[t] = rsqrtf(sk + 1e-6f);
  }
  __syncthreads();
#pragma unroll
  for (int i = 0; i < 32; i++) {
    int fi = t + i * 256;
    int c = fi >> 7, d = fi & 127;
    Qs[c][d] = f32_to_bf16(u2f(((unsigned)Qs[c][d]) << 16) * rqs[c]);
    Ks[c][d] = f32_to_bf16(u2f(((unsigned)Ks[c][d]) << 16) * rks[c]);
  }
  __syncthreads();

  int el = t >> 4, dg = t & 15;   // 16-lane DPP row = one el, 16 dg's
  float S[8];
#pragma unroll
  for (int i = 0; i < 8; i++)
    S[i] = state0[(size_t)h * 16384 + (size_t)(dg * 8 + i) * 128 + e0 + el];

  for (int c = 0; c < 64; c++) {
    float a = As[c], b = Bs[c];
    uint4 kr = *(const uint4*)&Ks[c][dg * 8];
    uint4 qr = *(const uint4*)&Qs[c][dg * 8];
    float kf[8], qf[8];
    kf[0] = bf16lo(kr.x); kf[1] = bf16hi(kr.x); kf[2] = bf16lo(kr.y); kf[3] = bf16hi(kr.y);
    kf[4] = bf16lo(kr.z); kf[5] = bf16hi(kr.z); kf[6] = bf16lo(kr.w); kf[7] = bf16hi(kr.w);
    qf[0] = bf16lo(qr.x); qf[1] = bf16hi(qr.x); qf[2] = bf16lo(qr.y); qf[3] = bf16hi(qr.y);
    qf[4] = bf16lo(qr.z); qf[5] = bf16hi(qr.z); qf[6] = bf16lo(qr.w); qf[7] = bf16hi(qr.w);

    float r0 = 0.f, r1 = 0.f;
#pragma unroll
    for (int i = 0; i < 4; i++) { S[i] *= a; r0 += S[i] * kf[i]; }
#pragma unroll
    for (int i = 4; i < 8; i++) { S[i] *= a; r1 += S[i] * kf[i]; }
    float rp = dpp16_sum(r0 + r1);            // full sum in all 16 lanes
    float ke = b * (Vs[c][el] - rp);

    float o0 = 0.f, o1 = 0.f;
#pragma unroll
    for (int i = 0; i < 4; i++) { S[i] += ke * kf[i]; o0 += S[i] * qf[i]; }
#pragma unroll
    for (int i = 4; i < 8; i++) { S[i] += ke * kf[i]; o1 += S[i] * qf[i]; }
    float op = dpp16_sum(o0 + o1);
    if (dg == 0) Os[c][el] = op;
  }
  __syncthreads();
  {
    int c = t >> 2, eq = (t & 3) * 4;
    unsigned short u[4];
#pragma unroll
    for (int j = 0; j < 4; j++) u[j] = f32_to_bf16(Os[c][eq + j]);
    uint2 p;
    p.x = (unsigned)u[0] | ((unsigned)u[1] << 16);
    p.y = (unsigned)u[2] | ((unsigned)u[3] << 16);
    *(uint2*)(obT + (size_t)c * 4096 + h * 128 + e0 + eq) = p;
  }
}

// ---------------------------------------------------------------------------
// kD: out += Wo @ ob (bias pre-initialized by kO). grid 256 = 128 row-tiles
// x 2 K-halves; fp32 atomicAdd epilogue.
// ---------------------------------------------------------------------------
__global__ __launch_bounds__(128) void kD(const float* __restrict__ Wo,
                                          const unsigned short* __restrict__ obT,
                                          float* __restrict__ out) {
  __shared__ struct { unsigned short Wt[32][136]; unsigned short Xt[64][136]; } sm;
  int t = threadIdx.x;
  int wr0 = (blockIdx.x & 127) * 32;
  int kh = blockIdx.x >> 7;               // K-half: 0 or 1
  int kbase = kh * 2048;
  int l = t & 63, w = t >> 6;
  int lo = l & 15, hi = l >> 4;

  f32x4 acc[4];
#pragma unroll
  for (int cf = 0; cf < 4; cf++) acc[cf] = f32x4{0.f, 0.f, 0.f, 0.f};

  for (int k0 = kbase; k0 < kbase + 2048; k0 += 128) {
    float4 wv[8];
#pragma unroll
    for (int i = 0; i < 8; i++) {
      int fi = t + i * 128;
      int row = fi >> 5, k4 = fi & 31;
      wv[i] = *(const float4*)(Wo + (size_t)(wr0 + row) * 4096 + k0 + k4 * 4);
    }
    uint4 xv[8];
#pragma unroll
    for (int i = 0; i < 8; i++) {
      int fi = t + i * 128;
      int c = fi >> 4, k8 = fi & 15;
      xv[i] = *(const uint4*)(obT + (size_t)c * 4096 + k0 + k8 * 8);
    }
#pragma unroll
    for (int i = 0; i < 8; i++) {
      int fi = t + i * 128;
      int row = fi >> 5, k4 = fi & 31;
      unsigned short u0 = f32_to_bf16(wv[i].x), u1 = f32_to_bf16(wv[i].y);
      unsigned short u2 = f32_to_bf16(wv[i].z), u3 = f32_to_bf16(wv[i].w);
      uint2 p;
      p.x = (unsigned)u0 | ((unsigned)u1 << 16);
      p.y = (unsigned)u2 | ((unsigned)u3 << 16);
      *(uint2*)&sm.Wt[row][k4 * 4] = p;
    }
#pragma unroll
    for (int i = 0; i < 8; i++) {
      int fi = t + i * 128;
      int c = fi >> 4, k8 = fi & 15;
      *(uint4*)&sm.Xt[c][k8 * 8] = xv[i];
    }
    __syncthreads();
#pragma unroll
    for (int ks = 0; ks < 128; ks += 32) {
      s16x8 a = *(const s16x8*)&sm.Wt[(w << 4) + lo][ks + hi * 8];
#pragma unroll
      for (int cf = 0; cf < 4; cf++) {
        s16x8 bfr = *(const s16x8*)&sm.Xt[cf * 16 + lo][ks + hi * 8];
        asm volatile("v_mfma_f32_16x16x32_bf16 %0, %1, %2, %0"
                     : "+v"(acc[cf]) : "v"(a), "v"(bfr));
      }
    }
    __syncthreads();
  }
  asm volatile("s_nop 7\n\ts_nop 7\n\ts_nop 7" ::);
#pragma unroll
  for (int p = 0; p < 4; p++) {
    int r = wr0 + (w << 4) + hi * 4 + p;
#pragma unroll
    for (int cf = 0; cf < 4; cf++)
      atomicAdd(out + (size_t)r * 64 + cf * 16 + lo, acc[cf][p]);
  }
}

// ---------------------------------------------------------------------------
extern "C" void kernel_launch(void* const* d_in, const int* in_sizes, int n_in,
                              void* d_out, int out_size, void* d_ws, size_t ws_size,
                              hipStream_t stream) {
  const float* hs  = (const float*)d_in[0];
  const float* Wq  = (const float*)d_in[1];
  const float* bq  = (const float*)d_in[2];
  const float* Wk  = (const float*)d_in[3];
  const float* bk  = (const float*)d_in[4];
  const float* Wv  = (const float*)d_in[5];
  const float* bv  = (const float*)d_in[6];
  const float* Wo  = (const float*)d_in[7];
  const float* bo  = (const float*)d_in[8];
  const float* cwq = (const float*)d_in[9];
  const float* cbq = (const float*)d_in[10];
  const float* cwk = (const float*)d_in[11];
  const float* cbk = (const float*)d_in[12];
  const float* cwv = (const float*)d_in[13];
  const float* cbv = (const float*)d_in[14];
  const float* Wa  = (const float*)d_in[15];
  const float* ba  = (const float*)d_in[16];
  const float* Wb  = (const float*)d_in[17];
  const float* bbb = (const float*)d_in[18];
  const float* st0 = (const float*)d_in[19];

  char* ws = (char*)d_ws;
  unsigned short* xhT = (unsigned short*)(ws);                       // 512 KB
  float* qkvb = (float*)(ws + (512 << 10));                          // 3 MB
  float* abuf = (float*)(ws + (512 << 10) + (3 << 20));              // 8 KB
  float* bbuf = (float*)(ws + (512 << 10) + (3 << 20) + 8192);       // 8 KB
  unsigned short* obT = (unsigned short*)(ws + (512 << 10) + (3 << 20) + 16384); // 512 KB

  float* outp = (float*)d_out;

  kO<<<dim3(256), dim3(256), 0, stream>>>(bo, outp);
  kX<<<dim3(64), dim3(256), 0, stream>>>(hs, xhT);
  kB<<<dim3(64), dim3(256), 0, stream>>>(Wa, ba, Wb, bbb, hs, abuf, bbuf);
  kA<<<dim3(384), dim3(128), 0, stream>>>(Wq, Wk, Wv, bq, bk, bv,
                                          cwq, cwk, cwv, cbq, cbk, cbv,
                                          xhT, qkvb);
  kC<<<dim3(256), dim3(256), 0, stream>>>(qkvb, abuf, bbuf, st0, obT);
  kD<<<dim3(256), dim3(128), 0, stream>>>(Wo, obT, outp);
}

// Round 6
// 368.755 us; speedup vs baseline: 1.3295x; 1.3295x over previous
//
#include <hip/hip_runtime.h>
#include <hip/hip_bf16.h>
#include <cstdint>
#include <cstddef>

typedef float f32x4 __attribute__((ext_vector_type(4)));
typedef short s16x8 __attribute__((ext_vector_type(8)));

__device__ inline unsigned short f32_to_bf16(float f) {
  union { float f; unsigned int u; } v; v.f = f;
  unsigned int u = v.u;
  u += 0x7fffu + ((u >> 16) & 1u);   // RNE
  return (unsigned short)(u >> 16);
}
__device__ inline float u2f(unsigned int u) {
  union { unsigned int u; float f; } v; v.u = u; return v.f;
}
__device__ inline float bf16lo(unsigned int w) { return u2f(w << 16); }
__device__ inline float bf16hi(unsigned int w) { return u2f(w & 0xffff0000u); }
__device__ inline unsigned int pkbf(float x, float y) {
  return (unsigned)f32_to_bf16(x) | ((unsigned)f32_to_bf16(y) << 16);
}

// 16-lane rotate-reduce via DPP row_ror (all 16 lanes end with the sum)
template <int CTRL>
__device__ inline float dpp_add(float x) {
  int v = __builtin_bit_cast(int, x);
  int r = __builtin_amdgcn_update_dpp(0, v, CTRL, 0xf, 0xf, true);
  return x + __builtin_bit_cast(float, r);
}
__device__ inline float dpp16_sum(float x) {
  x = dpp_add<0x121>(x);  // row_ror:1
  x = dpp_add<0x122>(x);  // row_ror:2
  x = dpp_add<0x124>(x);  // row_ror:4
  x = dpp_add<0x128>(x);  // row_ror:8
  return x;
}

// ---------------------------------------------------------------------------
// GEMM core: one wave computes C[16 rows][64 cols] over a private K-chunk.
// Wb = W + r0*4096 + kbase (fp32 rows), Xb = XT + kbase (bf16 [64][4096]).
// No LDS, no barriers, no staging: A loaded fp32->bf16 in-register, B from L2.
// ---------------------------------------------------------------------------
template <int ITERS>
__device__ inline void gcore(const float* __restrict__ Wb,
                             const unsigned short* __restrict__ Xb,
                             f32x4 (&acc)[4]) {
  int l = threadIdx.x & 63;
  int lo = l & 15, hi = l >> 4;
  const float* wp = Wb + (size_t)lo * 4096 + hi * 8;
  const unsigned short* xp = Xb + (size_t)lo * 4096 + hi * 8;
#pragma unroll 4
  for (int it = 0; it < ITERS; ++it) {
    float4 wa = *(const float4*)(wp + it * 32);
    float4 wz = *(const float4*)(wp + it * 32 + 4);
    union { s16x8 v; unsigned int u[4]; } A;
    A.u[0] = pkbf(wa.x, wa.y); A.u[1] = pkbf(wa.z, wa.w);
    A.u[2] = pkbf(wz.x, wz.y); A.u[3] = pkbf(wz.z, wz.w);
    s16x8 b0 = *(const s16x8*)(xp + it * 32);
    s16x8 b1 = *(const s16x8*)(xp + (size_t)16 * 4096 + it * 32);
    s16x8 b2 = *(const s16x8*)(xp + (size_t)32 * 4096 + it * 32);
    s16x8 b3 = *(const s16x8*)(xp + (size_t)48 * 4096 + it * 32);
    asm volatile("v_mfma_f32_16x16x32_bf16 %0, %1, %2, %0" : "+v"(acc[0]) : "v"(A.v), "v"(b0));
    asm volatile("v_mfma_f32_16x16x32_bf16 %0, %1, %2, %0" : "+v"(acc[1]) : "v"(A.v), "v"(b1));
    asm volatile("v_mfma_f32_16x16x32_bf16 %0, %1, %2, %0" : "+v"(acc[2]) : "v"(A.v), "v"(b2));
    asm volatile("v_mfma_f32_16x16x32_bf16 %0, %1, %2, %0" : "+v"(acc[3]) : "v"(A.v), "v"(b3));
  }
}

// ---------------------------------------------------------------------------
// kX: x fp32 [4096 h][64 c]  ->  xhT bf16 [64 c][4096 h]
// ---------------------------------------------------------------------------
__global__ __launch_bounds__(256) void kX(const float* __restrict__ x,
                                          unsigned short* __restrict__ xhT) {
  __shared__ float Ts[64][65];
  int t = threadIdx.x;
  int h0 = blockIdx.x * 64;
#pragma unroll
  for (int i = 0; i < 4; i++) {
    int fi = t + i * 256;
    int h = fi >> 4, c4 = fi & 15;
    float4 v = *(const float4*)(x + (size_t)(h0 + h) * 64 + c4 * 4);
    Ts[h][c4 * 4 + 0] = v.x; Ts[h][c4 * 4 + 1] = v.y;
    Ts[h][c4 * 4 + 2] = v.z; Ts[h][c4 * 4 + 3] = v.w;
  }
  __syncthreads();
  int c = t >> 2, q4 = t & 3;
#pragma unroll
  for (int half = 0; half < 2; half++) {
    int h8 = q4 * 8 + half * 32;
    unsigned short u[8];
#pragma unroll
    for (int j = 0; j < 8; j++) u[j] = f32_to_bf16(Ts[h8 + j][c]);
    uint4 p;
    p.x = (unsigned)u[0] | ((unsigned)u[1] << 16);
    p.y = (unsigned)u[2] | ((unsigned)u[3] << 16);
    p.z = (unsigned)u[4] | ((unsigned)u[5] << 16);
    p.w = (unsigned)u[6] | ((unsigned)u[7] << 16);
    *(uint4*)(xhT + (size_t)c * 4096 + h0 + h8) = p;
  }
}

// ---------------------------------------------------------------------------
// kB: alpha/beta = sigmoid(Wa/Wb @ x + b)
// ---------------------------------------------------------------------------
__global__ __launch_bounds__(256) void kB(const float* __restrict__ Wa,
                                          const float* __restrict__ ba,
                                          const float* __restrict__ Wb,
                                          const float* __restrict__ bbb,
                                          const float* __restrict__ x,
                                          float* __restrict__ ab,
                                          float* __restrict__ bb2) {
  __shared__ float red[256];
  int t = threadIdx.x;
  int row = blockIdx.x;            // 0..63
  int c = t & 63, kp = t >> 6;     // 4 k-parts of 1024
  const float* Wr = (row < 32) ? (Wa + (size_t)row * 4096)
                               : (Wb + (size_t)(row - 32) * 4096);
  int kb = kp * 1024;
  float a0 = 0.f, a1 = 0.f, a2 = 0.f, a3 = 0.f;
#pragma unroll 4
  for (int k = 0; k < 1024; k += 4) {
    a0 += Wr[kb + k + 0] * x[(size_t)(kb + k + 0) * 64 + c];
    a1 += Wr[kb + k + 1] * x[(size_t)(kb + k + 1) * 64 + c];
    a2 += Wr[kb + k + 2] * x[(size_t)(kb + k + 2) * 64 + c];
    a3 += Wr[kb + k + 3] * x[(size_t)(kb + k + 3) * 64 + c];
  }
  red[t] = (a0 + a1) + (a2 + a3);
  __syncthreads();
  if (t < 64) {
    float s = red[t] + red[t + 64] + red[t + 128] + red[t + 192];
    float z = s + (row < 32 ? ba[row] : bbb[row - 32]);
    float sg = 1.f / (1.f + __expf(-z));
    if (row < 32) ab[(size_t)row * 64 + t] = sg;
    else          bb2[(size_t)(row - 32) * 64 + t] = sg;
  }
}

// ---------------------------------------------------------------------------
// gA: fused QKV GEMM. 768 blocks (3 mats x 256 rowgroups) x 512 thr (8 waves).
// Wave w: rows rg*16..+15, K-chunk [w*512, w*512+512). Barrier-free loop,
// LDS tree-reduce, then bias+causal-conv+SiLU epilogue.
// ---------------------------------------------------------------------------
__global__ __launch_bounds__(512) void gA(
    const float* __restrict__ Wq, const float* __restrict__ Wk, const float* __restrict__ Wv,
    const float* __restrict__ bq, const float* __restrict__ bk, const float* __restrict__ bv,
    const float* __restrict__ cwq, const float* __restrict__ cwk, const float* __restrict__ cwv,
    const float* __restrict__ cbq, const float* __restrict__ cbk, const float* __restrict__ cbv,
    const unsigned short* __restrict__ xhT, float* __restrict__ qkvb) {
  __shared__ float red[8][1024];
  __shared__ float Qs[16][66];
  int t = threadIdx.x;
  int mat = blockIdx.x >> 8;          // 0..2
  int rg = blockIdx.x & 255;
  int wr0 = rg * 16;
  const float* W = (mat == 0) ? Wq : ((mat == 1) ? Wk : Wv);
  int w = t >> 6;

  f32x4 acc[4];
#pragma unroll
  for (int cf = 0; cf < 4; cf++) acc[cf] = f32x4{0.f, 0.f, 0.f, 0.f};
  gcore<16>(W + (size_t)wr0 * 4096 + w * 512, xhT + w * 512, acc);

  int l = t & 63, lo = l & 15, hi = l >> 4;
#pragma unroll
  for (int cf = 0; cf < 4; cf++)
#pragma unroll
    for (int p = 0; p < 4; p++)
      red[w][(hi * 4 + p) * 64 + cf * 16 + lo] = acc[cf][p];
  __syncthreads();

#pragma unroll
  for (int h2 = 0; h2 < 2; h2++) {
    int pos = t + h2 * 512;
    float s = 0.f;
#pragma unroll
    for (int ww = 0; ww < 8; ww++) s += red[ww][pos];
    Qs[pos >> 6][pos & 63] = s;
  }
  __syncthreads();

  if (t < 256) {
    const float* bmat = (mat == 0) ? bq : ((mat == 1) ? bk : bv);
    const float* cwm  = (mat == 0) ? cwq : ((mat == 1) ? cwk : cwv);
    const float* cbm  = (mat == 0) ? cbq : ((mat == 1) ? cbk : cbv);
    int row = t >> 4, c0 = (t & 15) * 4;
    int gr = wr0 + row;
    float bias = bmat[gr];
    float w0 = cwm[gr * 4 + 0], w1 = cwm[gr * 4 + 1];
    float w2 = cwm[gr * 4 + 2], w3 = cwm[gr * 4 + 3];
    float cbias = cbm[gr];
    float4 o;
    float* op = (float*)&o;
#pragma unroll
    for (int j = 0; j < 4; j++) {
      int c = c0 + j;
      float s = 0.f, v; int cc;
      cc = c - 3; v = (cc >= 0) ? (Qs[row][cc] + bias) : 0.f; s += v * w0;
      cc = c - 2; v = (cc >= 0) ? (Qs[row][cc] + bias) : 0.f; s += v * w1;
      cc = c - 1; v = (cc >= 0) ? (Qs[row][cc] + bias) : 0.f; s += v * w2;
      v = Qs[row][c] + bias; s += v * w3;
      float z = s + cbias;
      op[j] = z / (1.f + __expf(-z));
    }
    *(float4*)(qkvb + (size_t)(mat * 4096 + gr) * 64 + c0) = o;
  }
}

// ---------------------------------------------------------------------------
// gD: out = Wo @ ob + bo. 256 blocks x 1024 thr (16 waves, K=256 each).
// ---------------------------------------------------------------------------
__global__ __launch_bounds__(1024) void gD(const float* __restrict__ Wo,
                                           const float* __restrict__ bo,
                                           const unsigned short* __restrict__ obT,
                                           float* __restrict__ out) {
  __shared__ float red[16][1024];
  int t = threadIdx.x;
  int wr0 = blockIdx.x * 16;
  int w = t >> 6;

  f32x4 acc[4];
#pragma unroll
  for (int cf = 0; cf < 4; cf++) acc[cf] = f32x4{0.f, 0.f, 0.f, 0.f};
  gcore<8>(Wo + (size_t)wr0 * 4096 + w * 256, obT + w * 256, acc);

  int l = t & 63, lo = l & 15, hi = l >> 4;
#pragma unroll
  for (int cf = 0; cf < 4; cf++)
#pragma unroll
    for (int p = 0; p < 4; p++)
      red[w][(hi * 4 + p) * 64 + cf * 16 + lo] = acc[cf][p];
  __syncthreads();

  float s = 0.f;
#pragma unroll
  for (int ww = 0; ww < 16; ww++) s += red[ww][t];
  int row = t >> 6, col = t & 63;
  out[(size_t)(wr0 + row) * 64 + col] = s + bo[wr0 + row];
}

// ---------------------------------------------------------------------------
// kC: delta-rule scan (unchanged — verified pass). grid 256 = 32 heads x 8
// e-groups; DPP rotate-reduce; zero barriers in the 64-step loop.
// ---------------------------------------------------------------------------
__global__ __launch_bounds__(256) void kC(const float* __restrict__ qkvb,
                                          const float* __restrict__ ab,
                                          const float* __restrict__ bb2,
                                          const float* __restrict__ state0,
                                          unsigned short* __restrict__ obT) {
  __shared__ unsigned short Qs[64][136];  // [c][d] bf16, l2-normalized
  __shared__ unsigned short Ks[64][136];
  __shared__ float Vs[64][17];            // [c][e_local]
  __shared__ float Os[64][17];
  __shared__ float As[64], Bs[64];
  __shared__ float red[256], red2[256];
  __shared__ float rqs[64], rks[64];

  int t = threadIdx.x;
  int h = blockIdx.x >> 3, eg = blockIdx.x & 7;
  int e0 = eg * 16;

#pragma unroll
  for (int i = 0; i < 8; i++) {
    int fi = t + i * 256;
    int d = fi >> 4, c4 = fi & 15;
    float4 qv = *(const float4*)(qkvb + (size_t)(h * 128 + d) * 64 + c4 * 4);
    float4 kv = *(const float4*)(qkvb + (size_t)(4096 + h * 128 + d) * 64 + c4 * 4);
    const float* qp = (const float*)&qv;
    const float* kp = (const float*)&kv;
#pragma unroll
    for (int j = 0; j < 4; j++) {
      Qs[c4 * 4 + j][d] = f32_to_bf16(qp[j]);
      Ks[c4 * 4 + j][d] = f32_to_bf16(kp[j]);
    }
  }
  {
    int elr = t >> 4, c4 = t & 15;
    float4 vv = *(const float4*)(qkvb + (size_t)(8192 + h * 128 + e0 + elr) * 64 + c4 * 4);
    const float* vp = (const float*)&vv;
#pragma unroll
    for (int j = 0; j < 4; j++) Vs[c4 * 4 + j][elr] = vp[j];
  }
  if (t < 64) { As[t] = ab[h * 64 + t]; Bs[t] = bb2[h * 64 + t]; }
  __syncthreads();

  {
    int c = t >> 2, part = t & 3;
    float sq = 0.f, sk = 0.f;
#pragma unroll
    for (int j = 0; j < 32; j++) {
      float qv = u2f(((unsigned)Qs[c][part + 4 * j]) << 16);
      float kv = u2f(((unsigned)Ks[c][part + 4 * j]) << 16);
      sq += qv * qv; sk += kv * kv;
    }
    red[t] = sq; red2[t] = sk;
  }
  __syncthreads();
  if (t < 64) {
    float sq = red[t * 4] + red[t * 4 + 1] + red[t * 4 + 2] + red[t * 4 + 3];
    float sk = red2[t * 4] + red2[t * 4 + 1] + red2[t * 4 + 2] + red2[t * 4 + 3];
    rqs[t] = rsqrtf(sq + 1e-6f);
    rks[t] = rsqrtf(sk + 1e-6f);
  }
  __syncthreads();
#pragma unroll
  for (int i = 0; i < 32; i++) {
    int fi = t + i * 256;
    int c = fi >> 7, d = fi & 127;
    Qs[c][d] = f32_to_bf16(u2f(((unsigned)Qs[c][d]) << 16) * rqs[c]);
    Ks[c][d] = f32_to_bf16(u2f(((unsigned)Ks[c][d]) << 16) * rks[c]);
  }
  __syncthreads();

  int el = t >> 4, dg = t & 15;
  float S[8];
#pragma unroll
  for (int i = 0; i < 8; i++)
    S[i] = state0[(size_t)h * 16384 + (size_t)(dg * 8 + i) * 128 + e0 + el];

  for (int c = 0; c < 64; c++) {
    float a = As[c], b = Bs[c];
    uint4 kr = *(const uint4*)&Ks[c][dg * 8];
    uint4 qr = *(const uint4*)&Qs[c][dg * 8];
    float kf[8], qf[8];
    kf[0] = bf16lo(kr.x); kf[1] = bf16hi(kr.x); kf[2] = bf16lo(kr.y); kf[3] = bf16hi(kr.y);
    kf[4] = bf16lo(kr.z); kf[5] = bf16hi(kr.z); kf[6] = bf16lo(kr.w); kf[7] = bf16hi(kr.w);
    qf[0] = bf16lo(qr.x); qf[1] = bf16hi(qr.x); qf[2] = bf16lo(qr.y); qf[3] = bf16hi(qr.y);
    qf[4] = bf16lo(qr.z); qf[5] = bf16hi(qr.z); qf[6] = bf16lo(qr.w); qf[7] = bf16hi(qr.w);

    float r0 = 0.f, r1 = 0.f;
#pragma unroll
    for (int i = 0; i < 4; i++) { S[i] *= a; r0 += S[i] * kf[i]; }
#pragma unroll
    for (int i = 4; i < 8; i++) { S[i] *= a; r1 += S[i] * kf[i]; }
    float rp = dpp16_sum(r0 + r1);
    float ke = b * (Vs[c][el] - rp);

    float o0 = 0.f, o1 = 0.f;
#pragma unroll
    for (int i = 0; i < 4; i++) { S[i] += ke * kf[i]; o0 += S[i] * qf[i]; }
#pragma unroll
    for (int i = 4; i < 8; i++) { S[i] += ke * kf[i]; o1 += S[i] * qf[i]; }
    float op = dpp16_sum(o0 + o1);
    if (dg == 0) Os[c][el] = op;
  }
  __syncthreads();
  {
    int c = t >> 2, eq = (t & 3) * 4;
    unsigned short u[4];
#pragma unroll
    for (int j = 0; j < 4; j++) u[j] = f32_to_bf16(Os[c][eq + j]);
    uint2 p;
    p.x = (unsigned)u[0] | ((unsigned)u[1] << 16);
    p.y = (unsigned)u[2] | ((unsigned)u[3] << 16);
    *(uint2*)(obT + (size_t)c * 4096 + h * 128 + e0 + eq) = p;
  }
}

// ---------------------------------------------------------------------------
extern "C" void kernel_launch(void* const* d_in, const int* in_sizes, int n_in,
                              void* d_out, int out_size, void* d_ws, size_t ws_size,
                              hipStream_t stream) {
  const float* hs  = (const float*)d_in[0];
  const float* Wq  = (const float*)d_in[1];
  const float* bq  = (const float*)d_in[2];
  const float* Wk  = (const float*)d_in[3];
  const float* bk  = (const float*)d_in[4];
  const float* Wv  = (const float*)d_in[5];
  const float* bv  = (const float*)d_in[6];
  const float* Wo  = (const float*)d_in[7];
  const float* bo  = (const float*)d_in[8];
  const float* cwq = (const float*)d_in[9];
  const float* cbq = (const float*)d_in[10];
  const float* cwk = (const float*)d_in[11];
  const float* cbk = (const float*)d_in[12];
  const float* cwv = (const float*)d_in[13];
  const float* cbv = (const float*)d_in[14];
  const float* Wa  = (const float*)d_in[15];
  const float* ba  = (const float*)d_in[16];
  const float* Wb  = (const float*)d_in[17];
  const float* bbb = (const float*)d_in[18];
  const float* st0 = (const float*)d_in[19];

  char* ws = (char*)d_ws;
  unsigned short* xhT = (unsigned short*)(ws);                       // 512 KB
  float* qkvb = (float*)(ws + (512 << 10));                          // 3 MB
  float* abuf = (float*)(ws + (512 << 10) + (3 << 20));              // 8 KB
  float* bbuf = (float*)(ws + (512 << 10) + (3 << 20) + 8192);       // 8 KB
  unsigned short* obT = (unsigned short*)(ws + (512 << 10) + (3 << 20) + 16384); // 512 KB

  float* outp = (float*)d_out;

  kX<<<dim3(64), dim3(256), 0, stream>>>(hs, xhT);
  kB<<<dim3(64), dim3(256), 0, stream>>>(Wa, ba, Wb, bbb, hs, abuf, bbuf);
  gA<<<dim3(768), dim3(512), 0, stream>>>(Wq, Wk, Wv, bq, bk, bv,
                                          cwq, cwk, cwv, cbq, cbk, cbv,
                                          xhT, qkvb);
  kC<<<dim3(256), dim3(256), 0, stream>>>(qkvb, abuf, bbuf, st0, obT);
  gD<<<dim3(256), dim3(1024), 0, stream>>>(Wo, bo, obT, outp);
}